// Round 1
// baseline (817.896 us; speedup 1.0000x reference)
//
#include <hip/hip_runtime.h>

// CRF forward scan. B=512 batches, S=1024 steps, T=64 tags.
// new_alpha[b,i] = feat[b,s,i] + logsumexp_j(alpha[b,j] + trans[i,j])
//
// Transform: E[i,j] = exp(trans[i,j] - rowmax_i) precomputed once (trans is
// step-invariant). Per step this is a fp32 matvec:
//   new_alpha[i] = feat[i] + rowmax_i + M + log(sum_j E[i,j] * exp(alpha[j]-M))
// M = alpha[lane 1] proxy (spread is bounded ~15, exact max not needed for
// fp32 range safety). Tag 0 (trans row/col = -1e4) underflows to p=0 exactly,
// matching the fp32 reference behavior.

constexpr int T = 64;

__global__ __launch_bounds__(64)
void crf_fwd_kernel(const float* __restrict__ feats,
                    const float* __restrict__ masks,
                    const float* __restrict__ trans,
                    float* __restrict__ out,
                    int S)
{
    const int b    = blockIdx.x;
    const int lane = threadIdx.x;   // tag index i

    __shared__ float sh_p[T];       // broadcast buffer for p[j]

    // ---- one-time: load transitions row i=lane, rowmax, exponentiate ----
    float E[T];
    const float* tr = trans + lane * T;
    float rowmax = -3.4e38f;
#pragma unroll
    for (int j = 0; j < T; ++j) {
        E[j] = tr[j];
        rowmax = fmaxf(rowmax, E[j]);
    }
#pragma unroll
    for (int j = 0; j < T; ++j) {
        E[j] = __expf(E[j] - rowmax);   // in [0,1]
    }

    const float* fb = feats + (size_t)b * S * T;
    const float* mb = masks + (size_t)b * S;

    float alpha = fb[lane];            // alpha0 = feats[:,0]

    // software-pipelined next-step loads
    float feat = fb[T + lane];
    float m    = mb[1];

    for (int s = 1; s < S; ++s) {
        const int sn = (s + 1 < S) ? (s + 1) : (S - 1);
        const float feat_n = fb[sn * T + lane];
        const float m_n    = mb[sn];

        // range proxy (lane 1: first non-degenerate tag)
        const float M = __shfl(alpha, 1, 64);
        const float p = __expf(alpha - M);

        __syncthreads();               // WAR: prior iter's reads done
        sh_p[lane] = p;
        __syncthreads();               // RAW: p visible to all lanes

        // matvec row: acc = sum_j E[j] * p[j], 8 independent FMA chains
        const float4* shp4 = (const float4*)sh_p;
        float acc[8] = {0.f, 0.f, 0.f, 0.f, 0.f, 0.f, 0.f, 0.f};
#pragma unroll
        for (int q = 0; q < T / 4; ++q) {
            const float4 pv = shp4[q];     // lane-uniform addr -> LDS broadcast
            const int a0 = (q & 1) * 4;
            acc[a0 + 0] = fmaf(E[4 * q + 0], pv.x, acc[a0 + 0]);
            acc[a0 + 1] = fmaf(E[4 * q + 1], pv.y, acc[a0 + 1]);
            acc[a0 + 2] = fmaf(E[4 * q + 2], pv.z, acc[a0 + 2]);
            acc[a0 + 3] = fmaf(E[4 * q + 3], pv.w, acc[a0 + 3]);
        }
        const float total = ((acc[0] + acc[4]) + (acc[1] + acc[5]))
                          + ((acc[2] + acc[6]) + (acc[3] + acc[7]));

        const float na = feat + rowmax + M + __logf(total);
        alpha = m * na + (1.0f - m) * alpha;   // exact passthrough for m in {0,1}

        feat = feat_n;
        m    = m_n;
    }

    out[b * T + lane] = alpha;
}

extern "C" void kernel_launch(void* const* d_in, const int* in_sizes, int n_in,
                              void* d_out, int out_size, void* d_ws, size_t ws_size,
                              hipStream_t stream) {
    const float* feats = (const float*)d_in[0];   // (B, S, T) fp32
    const float* masks = (const float*)d_in[1];   // (B, S)    fp32
    const float* trans = (const float*)d_in[2];   // (T, T)    fp32
    float* out = (float*)d_out;                   // (B, T)    fp32

    const int S = 1024;                 // problem shape (B=512, S=1024, T=64)
    const int B = in_sizes[1] / S;

    crf_fwd_kernel<<<B, T, 0, stream>>>(feats, masks, trans, out, S);
}

// Round 2
// 610.104 us; speedup vs baseline: 1.3406x; 1.3406x over previous
//
#include <hip/hip_runtime.h>

// CRF forward scan. B=512 batches, S=1024 steps, T=64 tags.
// new_alpha[b,i] = feat[b,s,i] + logsumexp_j(alpha[b,j] + trans[i,j])
//
// E[i,j] = exp(trans[i,j] - rowmax_i) precomputed once; per step a fp32
// matvec + exp/log. M = alpha[lane 1] range-proxy (spread bounded; exact max
// unneeded for fp32 exp range). Tag 0 underflows to p=0 exactly.
//
// R2: block == one wave, so __syncthreads() (which drains vmcnt(0) and
// defeated the feat prefetch every step, ~1000 cyc/step) is replaced by
// wave-synchronous LDS + __builtin_amdgcn_wave_barrier() (zero-cost code
// motion fence; same-wave DS ops complete in order). Prefetch deepened to
// 2 steps so the global load has ~2 full steps of latency budget.

constexpr int T = 64;

__global__ __launch_bounds__(64)
void crf_fwd_kernel(const float* __restrict__ feats,
                    const float* __restrict__ masks,
                    const float* __restrict__ trans,
                    float* __restrict__ out,
                    int S)
{
    const int b    = blockIdx.x;
    const int lane = threadIdx.x;   // tag index i

    __shared__ float sh_p[T];       // broadcast buffer for p[j]

    // ---- one-time: load transitions row i=lane, rowmax, exponentiate ----
    float E[T];
    const float* tr = trans + lane * T;
    float rowmax = -3.4e38f;
#pragma unroll
    for (int j = 0; j < T; ++j) {
        E[j] = tr[j];
        rowmax = fmaxf(rowmax, E[j]);
    }
#pragma unroll
    for (int j = 0; j < T; ++j) {
        E[j] = __expf(E[j] - rowmax);   // in [0,1]
    }

    const float* fb = feats + (size_t)b * S * T;
    const float* mb = masks + (size_t)b * S;

    float alpha = fb[lane];            // alpha0 = feats[:,0]

    // 2-deep software pipeline for next-step feat/mask
    float feat0 = fb[T + lane];        // step 1
    float m0    = mb[1];
    float feat1 = fb[2 * T + lane];    // step 2
    float m1    = mb[2];

    for (int s = 1; s < S; ++s) {
        const int sp = (s + 2 < S) ? (s + 2) : (S - 1);
        const float feat_n = fb[sp * T + lane];
        const float m_n    = mb[sp];

        // range proxy M = alpha[lane 1] (first non-degenerate tag) via
        // readlane -> SGPR broadcast (cheaper than ds_bpermute)
        const float M = __int_as_float(
            __builtin_amdgcn_readlane(__float_as_int(alpha), 1));
        const float p = __expf(alpha - M);

        // wave-synchronous LDS exchange: no s_barrier, no vmcnt drain.
        __builtin_amdgcn_wave_barrier();
        sh_p[lane] = p;
        __builtin_amdgcn_wave_barrier();

        // load all 16 float4 (lane-uniform addr -> LDS broadcast), then FMA
        const float4* shp4 = (const float4*)sh_p;
        float4 pv[16];
#pragma unroll
        for (int q = 0; q < 16; ++q) pv[q] = shp4[q];

        float acc[8] = {0.f, 0.f, 0.f, 0.f, 0.f, 0.f, 0.f, 0.f};
#pragma unroll
        for (int q = 0; q < 16; ++q) {
            const int a0 = (q & 1) * 4;
            acc[a0 + 0] = fmaf(E[4 * q + 0], pv[q].x, acc[a0 + 0]);
            acc[a0 + 1] = fmaf(E[4 * q + 1], pv[q].y, acc[a0 + 1]);
            acc[a0 + 2] = fmaf(E[4 * q + 2], pv[q].z, acc[a0 + 2]);
            acc[a0 + 3] = fmaf(E[4 * q + 3], pv[q].w, acc[a0 + 3]);
        }
        const float total = ((acc[0] + acc[4]) + (acc[1] + acc[5]))
                          + ((acc[2] + acc[6]) + (acc[3] + acc[7]));

        const float na = feat0 + rowmax + M + __logf(total);
        alpha = m0 * na + (1.0f - m0) * alpha;  // exact passthrough for m in {0,1}

        feat0 = feat1; m0 = m1;
        feat1 = feat_n; m1 = m_n;
    }

    out[b * T + lane] = alpha;
}

extern "C" void kernel_launch(void* const* d_in, const int* in_sizes, int n_in,
                              void* d_out, int out_size, void* d_ws, size_t ws_size,
                              hipStream_t stream) {
    const float* feats = (const float*)d_in[0];   // (B, S, T) fp32
    const float* masks = (const float*)d_in[1];   // (B, S)    fp32
    const float* trans = (const float*)d_in[2];   // (T, T)    fp32
    float* out = (float*)d_out;                   // (B, T)    fp32

    const int S = 1024;                 // problem shape (B=512, S=1024, T=64)
    const int B = in_sizes[1] / S;

    crf_fwd_kernel<<<B, T, 0, stream>>>(feats, masks, trans, out, S);
}